// Round 1
// baseline (410.892 us; speedup 1.0000x reference)
//
#include <hip/hip_runtime.h>
#include <hip/hip_bf16.h>
#include <stdint.h>

// VQ: N=524288 rows, D=64, K=512 codes.
// out = [quantized (N*64 f32), vq_loss (1 f32)]
// loss = 1.1 * mean((q - w)^2) = 1.1 * sum_rows(||w - cb[best]||^2) / (N*D)
//      = 1.1 * sum_rows(x_sq + (e_sq[best] - 2*dot[best])) / (N*D)

#define N_ROWS 524288
#define DIM    64
#define KC     512
#define BM     256            // rows per block
#define THREADS 512           // 8 waves
#define GRID   (N_ROWS / BM)  // 2048

// d_ws layout:
//   [0, 2048)         e_sq f32[512]
//   [2048, 67584)     codebook bf16, XOR-swizzled image [512][64]
//   [67584, +GRID*4)  per-block loss partials f32
#define ESQ_OFF   0
#define CB_OFF    2048
#define IMG_BYTES 67584

typedef __attribute__((ext_vector_type(8))) short short8;   // 8 bf16 in 4 VGPRs
typedef __attribute__((ext_vector_type(4))) float floatx4;

typedef const __attribute__((address_space(1))) uint8_t* gptr_t;
typedef __attribute__((address_space(3))) uint8_t* lptr_t;

__device__ __forceinline__ unsigned short f32_to_bf16_rne(float f) {
    union { float f; uint32_t u; } v; v.f = f;
    uint32_t u = v.u;
    return (unsigned short)((u + 0x7FFFu + ((u >> 16) & 1u)) >> 16);
}

// ---------- prep: build swizzled bf16 codebook image + e_sq in d_ws ----------
// grid 32 x 256; thread t of block b: row = b*16 + t/16, cols (t%16)*4 .. +4
__global__ void vq_prep(const float* __restrict__ cb, char* __restrict__ ws) {
    int t = threadIdx.x;
    int row = blockIdx.x * 16 + (t >> 4);
    int q4 = (t & 15) * 4;
    float4 v = *(const float4*)(cb + row * 64 + q4);
    // e_sq: reduce 16 lanes of same row (lanes grouped by t>>4 within wave)
    float p = v.x * v.x + v.y * v.y + v.z * v.z + v.w * v.w;
    p += __shfl_xor(p, 1); p += __shfl_xor(p, 2);
    p += __shfl_xor(p, 4); p += __shfl_xor(p, 8);
    if ((t & 15) == 0) ((float*)(ws + ESQ_OFF))[row] = p;
    // bf16 swizzled write: element index k -> k ^ ((row&7)<<3)  (16B slot XOR)
    int xr = (row & 7) << 3;
    ushort4 b;
    b.x = f32_to_bf16_rne(v.x); b.y = f32_to_bf16_rne(v.y);
    b.z = f32_to_bf16_rne(v.z); b.w = f32_to_bf16_rne(v.w);
    *(ushort4*)(ws + CB_OFF + row * 128 + ((q4 ^ xr) * 2)) = b;
}

// ---------- main ----------
__global__ __launch_bounds__(THREADS, 2) void vq_main(
    const float* __restrict__ w, const float* __restrict__ cbf,
    float* __restrict__ out, const char* __restrict__ ws_img,
    float* __restrict__ partials)
{
    __shared__ __align__(16) unsigned char smem[IMG_BYTES + 64];
    const int tid  = threadIdx.x;
    const int wave = tid >> 6;
    const int lane = tid & 63;
    const int g    = lane >> 4;   // k-group within fragment
    const int lc   = lane & 15;   // row (A) / col (B,D) within fragment

    // ---- stage 66KB image: linear global_load_lds, 1KB per wave-issue ----
    {
        const char* src = ws_img;
        #pragma unroll
        for (int i = 0; i < 8; ++i) {
            int off = (wave * 8 + i) * 1024;
            __builtin_amdgcn_global_load_lds((gptr_t)(src + off + lane * 16),
                                             (lptr_t)(smem + off), 16, 0, 0);
        }
        if (wave == 0) {
            #pragma unroll
            for (int i = 64; i < 66; ++i) {
                int off = i * 1024;
                __builtin_amdgcn_global_load_lds((gptr_t)(src + off + lane * 16),
                                                 (lptr_t)(smem + off), 16, 0, 0);
            }
        }
    }

    // ---- A fragments: wave handles rows rowbase + t*16 + {0..15}, t=0,1 ----
    // lane holds A[row=lc][k = s*32 + g*8 + j]; same sigma(g,j) used for B,
    // so any HW k-slot permutation cancels in the dot product.
    const int rowbase = blockIdx.x * BM + wave * 32;
    short8 afrag[2][2];
    float xsq[2];
    #pragma unroll
    for (int t = 0; t < 2; ++t) {
        int row = rowbase + t * 16 + lc;
        const float* wr = w + (size_t)row * 64 + g * 8;
        float4 f0 = *(const float4*)(wr);
        float4 f1 = *(const float4*)(wr + 4);
        float4 f2 = *(const float4*)(wr + 32);
        float4 f3 = *(const float4*)(wr + 36);
        float p = f0.x*f0.x + f0.y*f0.y + f0.z*f0.z + f0.w*f0.w
                + f1.x*f1.x + f1.y*f1.y + f1.z*f1.z + f1.w*f1.w
                + f2.x*f2.x + f2.y*f2.y + f2.z*f2.z + f2.w*f2.w
                + f3.x*f3.x + f3.y*f3.y + f3.z*f3.z + f3.w*f3.w;
        p += __shfl_xor(p, 16); p += __shfl_xor(p, 32);
        xsq[t] = p;  // x_sq of row (t*16 + lc), replicated across g
        short8 a0, a1;
        a0[0]=f32_to_bf16_rne(f0.x); a0[1]=f32_to_bf16_rne(f0.y);
        a0[2]=f32_to_bf16_rne(f0.z); a0[3]=f32_to_bf16_rne(f0.w);
        a0[4]=f32_to_bf16_rne(f1.x); a0[5]=f32_to_bf16_rne(f1.y);
        a0[6]=f32_to_bf16_rne(f1.z); a0[7]=f32_to_bf16_rne(f1.w);
        a1[0]=f32_to_bf16_rne(f2.x); a1[1]=f32_to_bf16_rne(f2.y);
        a1[2]=f32_to_bf16_rne(f2.z); a1[3]=f32_to_bf16_rne(f2.w);
        a1[4]=f32_to_bf16_rne(f3.x); a1[5]=f32_to_bf16_rne(f3.y);
        a1[6]=f32_to_bf16_rne(f3.z); a1[7]=f32_to_bf16_rne(f3.w);
        afrag[t][0] = a0; afrag[t][1] = a1;
    }
    __syncthreads();   // drains vmcnt -> staged LDS valid

    // ---- K-loop over 32 col-blocks of 16 codes ----
    const int xr  = (lc & 7) << 3;
    const int bb0 = CB_OFF + lc * 128 + (((g * 8) ^ xr) * 2);
    const int bb1 = CB_OFF + lc * 128 + (((g * 8 + 32) ^ xr) * 2);
    float best[2][4]; int bidx[2][4];
    #pragma unroll
    for (int t = 0; t < 2; ++t)
        #pragma unroll
        for (int r = 0; r < 4; ++r) { best[t][r] = 3.0e38f; bidx[t][r] = 0; }

    #pragma unroll
    for (int c = 0; c < 32; ++c) {
        float  es = *(const float*)(smem + ESQ_OFF + c * 64 + lc * 4);
        short8 b0 = *(const short8*)(smem + bb0 + c * 2048);
        short8 b1 = *(const short8*)(smem + bb1 + c * 2048);
        const int col = c * 16 + lc;
        #pragma unroll
        for (int t = 0; t < 2; ++t) {
            floatx4 acc = {0.f, 0.f, 0.f, 0.f};
            acc = __builtin_amdgcn_mfma_f32_16x16x32_bf16(afrag[t][0], b0, acc, 0, 0, 0);
            acc = __builtin_amdgcn_mfma_f32_16x16x32_bf16(afrag[t][1], b1, acc, 0, 0, 0);
            #pragma unroll
            for (int r = 0; r < 4; ++r) {
                float sc = fmaf(-2.0f, acc[r], es);   // e_sq - 2*dot
                if (sc < best[t][r]) { best[t][r] = sc; bidx[t][r] = col; }
            }
        }
    }

    // ---- argmin across the 16 lanes of each k-group (col classes) ----
    #pragma unroll
    for (int t = 0; t < 2; ++t)
        #pragma unroll
        for (int r = 0; r < 4; ++r) {
            float b = best[t][r]; int i = bidx[t][r];
            #pragma unroll
            for (int d = 1; d < 16; d <<= 1) {
                float ob = __shfl_xor(b, d);
                int   oi = __shfl_xor(i, d);
                if (ob < b || (ob == b && oi < i)) { b = ob; i = oi; }
            }
            best[t][r] = b; bidx[t][r] = i;
        }

    // ---- write quantized rows: D row = g*4 + r, 16 lanes x float4 = 256B ----
    #pragma unroll
    for (int t = 0; t < 2; ++t)
        #pragma unroll
        for (int r = 0; r < 4; ++r) {
            int row = rowbase + t * 16 + g * 4 + r;
            int idx = bidx[t][r];
            float4 v = *(const float4*)(cbf + (size_t)idx * 64 + lc * 4);
            *(float4*)(out + (size_t)row * 64 + lc * 4) = v;
        }

    // ---- loss partial: sum over wave's 32 rows of (x_sq + best_score) ----
    // full-wave sum of xsq counts each row 4x; of best counts each 16x.
    float v = (xsq[0] + xsq[1]) * 0.25f
            + (best[0][0] + best[0][1] + best[0][2] + best[0][3]
             + best[1][0] + best[1][1] + best[1][2] + best[1][3]) * 0.0625f;
    #pragma unroll
    for (int d = 1; d < 64; d <<= 1) v += __shfl_xor(v, d);
    float* lslot = (float*)(smem + IMG_BYTES);
    if (lane == 0) lslot[wave] = v;
    __syncthreads();
    if (tid == 0) {
        float s = 0.f;
        #pragma unroll
        for (int i = 0; i < 8; ++i) s += lslot[i];
        partials[blockIdx.x] = s;
    }
}

// ---------- finalize: reduce partials -> loss scalar ----------
__global__ void vq_finalize(const float* __restrict__ partials,
                            float* __restrict__ out_loss) {
    int tid = threadIdx.x;
    double s = 0.0;
    for (int i = tid; i < GRID; i += 256) s += (double)partials[i];
    #pragma unroll
    for (int d = 1; d < 64; d <<= 1) s += __shfl_xor(s, d);
    __shared__ double sd[4];
    if ((tid & 63) == 0) sd[tid >> 6] = s;
    __syncthreads();
    if (tid == 0) {
        double tot = sd[0] + sd[1] + sd[2] + sd[3];
        *out_loss = (float)(tot * (1.1 / 33554432.0));
    }
}

extern "C" void kernel_launch(void* const* d_in, const int* in_sizes, int n_in,
                              void* d_out, int out_size, void* d_ws, size_t ws_size,
                              hipStream_t stream) {
    const float* w  = (const float*)d_in[0];
    const float* cb = (const float*)d_in[1];
    float* out = (float*)d_out;
    char*  ws  = (char*)d_ws;
    float* partials = (float*)(ws + IMG_BYTES);

    vq_prep<<<32, 256, 0, stream>>>(cb, ws);
    vq_main<<<GRID, THREADS, 0, stream>>>(w, cb, out, ws, partials);
    vq_finalize<<<1, 256, 0, stream>>>(partials, out + (size_t)N_ROWS * DIM);
}